// Round 1
// baseline (2161.791 us; speedup 1.0000x reference)
//
#include <hip/hip_runtime.h>

#define NN 2000
#define BB 8

// ---------------------------------------------------------------------------
// ws layout (floats):
//   adjW3 : NN*NN            adj@W3^T + b3
//   m     : BB*NN*NN         relu(d1@W2^T + b2 + adjW3) + I   (shared by both graph convs)
//   dinv  : BB*NN            rsqrt(rowsum(m))
//   z     : BB*NN*128        x @ W^T  (reused for conv1 (128) and conv2 (64))
//   conc  : BB*NN*128        graph-conv-1 output == conc_flat
//   avg/mx/ca : BB*128 each
//   s0/s1 : BB*NN
//   rh/u/cpre : BB*NN*64 each
// total ~173 MB
// ---------------------------------------------------------------------------

__device__ __forceinline__ float sigf(float x) { return 1.0f / (1.0f + expf(-x)); }

// ---------------------------------------------------------------------------
// C = A @ B^T (+bias). MODE 0: adjW3 = adj@W3^T + b3 (grid.z=1)
// MODE 1: m[b] = relu(d1(windd,wn[b]) @ W2^T + b2 + adjW3) + I  (grid.z=BB)
// 128x128 tile, 8x8 micro, TK=16. 2000 = 125*16 exactly (no k guards).
// ---------------------------------------------------------------------------
template<int MODE>
__global__ __launch_bounds__(256) void k_gemm_nt(
    const float* __restrict__ A, const float* __restrict__ Bm,
    const float* __restrict__ bias, const float* __restrict__ adjW3,
    const float* __restrict__ inputs, float* __restrict__ C)
{
    __shared__ float as[16][132];
    __shared__ float bs[16][132];
    const int t  = threadIdx.x;
    const int i0 = blockIdx.x * 128;
    const int j0 = blockIdx.y * 128;
    const int b  = blockIdx.z;

    const int row_off = t >> 1;        // 0..127 (one tile row per 2 threads)
    const int khalf   = (t & 1) * 8;   // 0 or 8
    int arow = i0 + row_off; if (arow >= NN) arow = NN - 1;   // clamp: safe garbage, write-guarded
    int brow = j0 + row_off; if (brow >= NN) brow = NN - 1;
    const float* aptr = A  + (size_t)arow * NN + khalf;
    const float* bptr = Bm + (size_t)brow * NN + khalf;
    float wn = 0.0f;
    if (MODE == 1) wn = inputs[(size_t)b * 3 * NN + 2 * NN + arow] * 360.0f;

    float acc[8][8];
#pragma unroll
    for (int r = 0; r < 8; ++r)
#pragma unroll
        for (int c = 0; c < 8; ++c) acc[r][c] = 0.0f;

    const int r0 = (t & 15) * 8;
    const int c0 = (t >> 4) * 8;

    for (int k0 = 0; k0 < NN; k0 += 16) {
        float4 a0 = *(const float4*)(aptr + k0);
        float4 a1 = *(const float4*)(aptr + k0 + 4);
        float4 b0 = *(const float4*)(bptr + k0);
        float4 b1 = *(const float4*)(bptr + k0 + 4);
        if (MODE == 1) {
            float av[8] = {a0.x,a0.y,a0.z,a0.w,a1.x,a1.y,a1.z,a1.w};
#pragma unroll
            for (int q = 0; q < 8; ++q) {
                float d = fabsf(av[q] - wn);
                d = (d > 360.0f) ? 180.0f : d;
                av[q] = fmaxf(__cosf(d * 0.017453292519943295f), 0.0f);
            }
            a0 = make_float4(av[0],av[1],av[2],av[3]);
            a1 = make_float4(av[4],av[5],av[6],av[7]);
        }
        __syncthreads();
        as[khalf+0][row_off]=a0.x; as[khalf+1][row_off]=a0.y;
        as[khalf+2][row_off]=a0.z; as[khalf+3][row_off]=a0.w;
        as[khalf+4][row_off]=a1.x; as[khalf+5][row_off]=a1.y;
        as[khalf+6][row_off]=a1.z; as[khalf+7][row_off]=a1.w;
        bs[khalf+0][row_off]=b0.x; bs[khalf+1][row_off]=b0.y;
        bs[khalf+2][row_off]=b0.z; bs[khalf+3][row_off]=b0.w;
        bs[khalf+4][row_off]=b1.x; bs[khalf+5][row_off]=b1.y;
        bs[khalf+6][row_off]=b1.z; bs[khalf+7][row_off]=b1.w;
        __syncthreads();
#pragma unroll
        for (int k = 0; k < 16; ++k) {
            float4 x0 = *(const float4*)&as[k][r0];
            float4 x1 = *(const float4*)&as[k][r0 + 4];
            float4 y0 = *(const float4*)&bs[k][c0];
            float4 y1 = *(const float4*)&bs[k][c0 + 4];
            float ar[8] = {x0.x,x0.y,x0.z,x0.w,x1.x,x1.y,x1.z,x1.w};
            float br[8] = {y0.x,y0.y,y0.z,y0.w,y1.x,y1.y,y1.z,y1.w};
#pragma unroll
            for (int r = 0; r < 8; ++r)
#pragma unroll
                for (int c = 0; c < 8; ++c)
                    acc[r][c] = fmaf(ar[r], br[c], acc[r][c]);
        }
    }

#pragma unroll
    for (int r = 0; r < 8; ++r) {
        int i = i0 + r0 + r;
        if (i >= NN) continue;
#pragma unroll
        for (int c = 0; c < 8; ++c) {
            int j = j0 + c0 + c;
            if (j >= NN) continue;
            float v = acc[r][c] + bias[j];
            if (MODE == 0) {
                C[(size_t)i * NN + j] = v;
            } else {
                v += adjW3[(size_t)i * NN + j];
                v = fmaxf(v, 0.0f);
                if (i == j) v += 1.0f;
                C[(size_t)b * NN * NN + (size_t)i * NN + j] = v;
            }
        }
    }
}

// dinv[row] = rsqrt(sum_j m[row, j]),  row = b*NN + i
__global__ __launch_bounds__(256) void k_rowsum(const float* __restrict__ m, float* __restrict__ dinv)
{
    const int row = blockIdx.x;
    const float* p = m + (size_t)row * NN;
    float s = 0.0f;
    for (int j = threadIdx.x; j < NN; j += 256) s += p[j];
#pragma unroll
    for (int off = 32; off > 0; off >>= 1) s += __shfl_down(s, off);
    __shared__ float red[4];
    if ((threadIdx.x & 63) == 0) red[threadIdx.x >> 6] = s;
    __syncthreads();
    if (threadIdx.x == 0) dinv[row] = rsqrtf(red[0] + red[1] + red[2] + red[3]);
}

// z[b,j,o] = sum_c x[b,j,c] * W[o,c];  x = [inputs(ch0), hsrc(64)]
template<int OUT>
__global__ __launch_bounds__(128) void k_xw(
    const float* __restrict__ inputs, const float* __restrict__ hsrc,
    const float* __restrict__ W, float* __restrict__ z)
{
    const int b  = blockIdx.y;
    const int j0 = blockIdx.x * 16;
    const int t  = threadIdx.x;
    __shared__ float wl[OUT * 65];
    __shared__ float xs[16 * 66];
    for (int idx = t; idx < OUT * 65; idx += OUT) wl[idx] = W[idx];
    for (int idx = t; idx < 16 * 64; idx += OUT) {
        int jj = idx >> 6, hh = idx & 63;
        xs[jj * 66 + 1 + hh] = hsrc[(size_t)b * NN * 64 + (size_t)(j0 + jj) * 64 + hh];
    }
    if (t < 16) xs[t * 66] = inputs[(size_t)b * 3 * NN + (j0 + t)];
    __syncthreads();
    const float* wrow = &wl[t * 65];
    for (int jj = 0; jj < 16; ++jj) {
        float acc = 0.0f;
        const float* xr = &xs[jj * 66];
#pragma unroll
        for (int c = 0; c < 65; ++c) acc = fmaf(xr[c], wrow[c], acc);
        z[(size_t)b * NN * OUT + (size_t)(j0 + jj) * OUT + t] = acc;
    }
}

// y[b,i,o0+oc] = dinv[b,i] * sum_j m[b,i,j] * dinv[b,j] * z[b,j,o] + bias[o]
// 64(i) x 64(o) tile, 4x4 micro, TK=32.
__global__ __launch_bounds__(256) void k_agg(
    const float* __restrict__ m, const float* __restrict__ dinv,
    const float* __restrict__ z, const float* __restrict__ bias,
    float* __restrict__ y, int OUT)
{
    __shared__ float msT[32][72];
    __shared__ float zs[32][68];
    const int t  = threadIdx.x;
    const int b  = blockIdx.z;
    const int i0 = blockIdx.x * 64;
    const int o0 = blockIdx.y * 64;

    const int ri = t & 15, ci = t >> 4;
    const int rr = t >> 2, kq = t & 3;     // msT staging
    const int zjj = t >> 3, zoq = t & 7;   // zs staging

    float acc[4][4];
#pragma unroll
    for (int r = 0; r < 4; ++r)
#pragma unroll
        for (int c = 0; c < 4; ++c) acc[r][c] = 0.0f;

    for (int j0 = 0; j0 < NN; j0 += 32) {
        const float* mp = m + (size_t)b * NN * NN + (size_t)(i0 + rr) * NN + j0 + kq * 8;
        float4 m0 = *(const float4*)(mp);
        float4 m1 = *(const float4*)(mp + 4);
        float4 z0 = make_float4(0,0,0,0), z1 = make_float4(0,0,0,0);
        int jz = j0 + zjj;
        if (jz < NN) {
            float dj = dinv[b * NN + jz];
            const float* zp = z + (size_t)b * NN * OUT + (size_t)jz * OUT + o0 + zoq * 8;
            z0 = *(const float4*)zp;
            z1 = *(const float4*)(zp + 4);
            z0.x *= dj; z0.y *= dj; z0.z *= dj; z0.w *= dj;
            z1.x *= dj; z1.y *= dj; z1.z *= dj; z1.w *= dj;
        }
        __syncthreads();
        msT[kq*8+0][rr] = m0.x; msT[kq*8+1][rr] = m0.y;
        msT[kq*8+2][rr] = m0.z; msT[kq*8+3][rr] = m0.w;
        msT[kq*8+4][rr] = m1.x; msT[kq*8+5][rr] = m1.y;
        msT[kq*8+6][rr] = m1.z; msT[kq*8+7][rr] = m1.w;
        *(float4*)&zs[zjj][zoq * 8]     = z0;
        *(float4*)&zs[zjj][zoq * 8 + 4] = z1;
        __syncthreads();
#pragma unroll
        for (int jj = 0; jj < 32; ++jj) {
            float4 av = *(const float4*)&msT[jj][ri * 4];
            float4 bv = *(const float4*)&zs[jj][ci * 4];
            float ar[4] = {av.x, av.y, av.z, av.w};
            float br[4] = {bv.x, bv.y, bv.z, bv.w};
#pragma unroll
            for (int r = 0; r < 4; ++r)
#pragma unroll
                for (int c = 0; c < 4; ++c)
                    acc[r][c] = fmaf(ar[r], br[c], acc[r][c]);
        }
    }

#pragma unroll
    for (int r = 0; r < 4; ++r) {
        int i = i0 + ri * 4 + r;
        if (i >= NN) continue;
        float di = dinv[b * NN + i];
#pragma unroll
        for (int c = 0; c < 4; ++c) {
            int o = o0 + ci * 4 + c;
            y[(size_t)b * NN * OUT + (size_t)i * OUT + o] = acc[r][c] * di + bias[o];
        }
    }
}

// per (b,c): mean & max over the contiguous 2000-chunk conc[b, c*2000 : +2000]
__global__ __launch_bounds__(256) void k_chred(const float* __restrict__ conc,
                                               float* __restrict__ avg, float* __restrict__ mx)
{
    const int bc = blockIdx.x;
    const float* p = conc + (size_t)bc * NN;
    float s = 0.0f, mv = -3.402823466e+38f;
    for (int n = threadIdx.x; n < NN; n += 256) { float v = p[n]; s += v; mv = fmaxf(mv, v); }
#pragma unroll
    for (int off = 32; off > 0; off >>= 1) {
        s += __shfl_down(s, off);
        mv = fmaxf(mv, __shfl_down(mv, off));
    }
    __shared__ float rs[4], rm[4];
    if ((threadIdx.x & 63) == 0) { rs[threadIdx.x >> 6] = s; rm[threadIdx.x >> 6] = mv; }
    __syncthreads();
    if (threadIdx.x == 0) {
        avg[bc] = (rs[0] + rs[1] + rs[2] + rs[3]) * (1.0f / NN);
        mx[bc]  = fmaxf(fmaxf(rm[0], rm[1]), fmaxf(rm[2], rm[3]));
    }
}

// ca[b,o] = sigmoid( Wca2 @ (relu(Wca1@avg) + relu(Wca1@mx)) )[o]
__global__ __launch_bounds__(128) void k_ca(
    const float* __restrict__ avg, const float* __restrict__ mx,
    const float* __restrict__ Wca1, const float* __restrict__ Wca2, float* __restrict__ ca)
{
    const int b = blockIdx.x, t = threadIdx.x;
    __shared__ float av[128], mv[128], h[16];
    av[t] = avg[b * 128 + t];
    mv[t] = mx[b * 128 + t];
    __syncthreads();
    if (t < 16) {
        int o8 = t & 7;
        const float* src = (t < 8) ? av : mv;
        float s = 0.0f;
        for (int c = 0; c < 128; ++c) s = fmaf(Wca1[o8 * 128 + c], src[c], s);
        h[t] = fmaxf(s, 0.0f);
    }
    __syncthreads();
    float s = 0.0f;
#pragma unroll
    for (int k = 0; k < 8; ++k) s = fmaf(Wca2[t * 8 + k], h[k] + h[8 + k], s);
    ca[b * 128 + t] = sigf(s);
}

// s0/s1: mean/max over channels of ca[c]*conc[b,c,n]
__global__ __launch_bounds__(256) void k_sat(
    const float* __restrict__ conc, const float* __restrict__ ca,
    float* __restrict__ s0, float* __restrict__ s1)
{
    const int b = blockIdx.y;
    const int n = blockIdx.x * 256 + threadIdx.x;
    __shared__ float cas[128];
    if (threadIdx.x < 128) cas[threadIdx.x] = ca[b * 128 + threadIdx.x];
    __syncthreads();
    if (n >= NN) return;
    float sm = 0.0f, sx = -3.402823466e+38f;
    for (int c = 0; c < 128; ++c) {
        float v = cas[c] * conc[(size_t)b * NN * 128 + (size_t)c * NN + n];
        sm += v; sx = fmaxf(sx, v);
    }
    s0[b * NN + n] = sm * (1.0f / 128.0f);
    s1[b * NN + n] = sx;
}

// spatial-attention conv7 + gates: writes rh = r*hidden and u
__global__ __launch_bounds__(256) void k_gate(
    const float* __restrict__ conc, const float* __restrict__ ca,
    const float* __restrict__ s0, const float* __restrict__ s1,
    const float* __restrict__ Wsa, const float* __restrict__ hidden,
    float* __restrict__ rh, float* __restrict__ u)
{
    const int b = blockIdx.y;
    const int n = blockIdx.x * 256 + threadIdx.x;
    __shared__ float cas[128];
    __shared__ float wsa[14];
    if (threadIdx.x < 128) cas[threadIdx.x] = ca[b * 128 + threadIdx.x];
    if (threadIdx.x < 14) wsa[threadIdx.x] = Wsa[threadIdx.x];
    __syncthreads();
    if (n >= NN) return;
    float sa = 0.0f;
#pragma unroll
    for (int k = 0; k < 7; ++k) {
        int nn = n + k - 3;
        if (nn >= 0 && nn < NN)
            sa += wsa[k] * s0[b * NN + nn] + wsa[7 + k] * s1[b * NN + nn];
    }
    float gs = sigf(sa);
    for (int c = 0; c < 128; ++c) {
        float v = gs * cas[c] * conc[(size_t)b * NN * 128 + (size_t)c * NN + n];
        float g = sigf(v);
        if (c < 64)
            rh[(size_t)b * NN * 64 + (size_t)c * NN + n] =
                g * hidden[(size_t)b * NN * 64 + (size_t)c * NN + n];
        else
            u[(size_t)b * NN * 64 + (size_t)(c - 64) * NN + n] = g;
    }
}

// out = u*h + (1-u)*tanh(cpre)
__global__ __launch_bounds__(256) void k_fin(
    const float* __restrict__ u, const float* __restrict__ hidden,
    const float* __restrict__ cpre, float* __restrict__ out)
{
    const size_t idx = (size_t)blockIdx.x * 256 + threadIdx.x;
    if (idx >= (size_t)BB * NN * 64) return;
    float uu = u[idx];
    out[idx] = uu * hidden[idx] + (1.0f - uu) * tanhf(cpre[idx]);
}

extern "C" void kernel_launch(void* const* d_in, const int* in_sizes, int n_in,
                              void* d_out, int out_size, void* d_ws, size_t ws_size,
                              hipStream_t stream)
{
    (void)in_sizes; (void)n_in; (void)out_size; (void)ws_size;
    const float* inputs = (const float*)d_in[0];
    const float* hidden = (const float*)d_in[1];
    const float* adj    = (const float*)d_in[2];
    const float* windd  = (const float*)d_in[3];
    const float* W2     = (const float*)d_in[4];
    const float* b2     = (const float*)d_in[5];
    const float* W3     = (const float*)d_in[6];
    const float* b3     = (const float*)d_in[7];
    const float* W1a    = (const float*)d_in[8];
    const float* b1a    = (const float*)d_in[9];
    const float* W1b    = (const float*)d_in[10];
    const float* b1b    = (const float*)d_in[11];
    const float* Wca1   = (const float*)d_in[12];
    const float* Wca2   = (const float*)d_in[13];
    const float* Wsa    = (const float*)d_in[14];
    float* out = (float*)d_out;

    float* ws    = (float*)d_ws;
    float* adjW3 = ws;
    float* mbuf  = adjW3 + (size_t)NN * NN;
    float* dinv  = mbuf + (size_t)BB * NN * NN;
    float* zbuf  = dinv + (size_t)BB * NN;
    float* conc  = zbuf + (size_t)BB * NN * 128;
    float* avg   = conc + (size_t)BB * NN * 128;
    float* mxb   = avg + BB * 128;
    float* ca    = mxb + BB * 128;
    float* s0    = ca + BB * 128;
    float* s1    = s0 + BB * NN;
    float* rh    = s1 + BB * NN;
    float* ubuf  = rh + (size_t)BB * NN * 64;
    float* cpre  = ubuf + (size_t)BB * NN * 64;

    k_gemm_nt<0><<<dim3(16, 16, 1), 256, 0, stream>>>(adj, W3, b3, nullptr, nullptr, adjW3);
    k_gemm_nt<1><<<dim3(16, 16, BB), 256, 0, stream>>>(windd, W2, b2, adjW3, inputs, mbuf);
    k_rowsum<<<BB * NN, 256, 0, stream>>>(mbuf, dinv);
    k_xw<128><<<dim3(125, BB), 128, 0, stream>>>(inputs, hidden, W1a, zbuf);
    k_agg<<<dim3(32, 2, BB), 256, 0, stream>>>(mbuf, dinv, zbuf, b1a, conc, 128);
    k_chred<<<BB * 128, 256, 0, stream>>>(conc, avg, mxb);
    k_ca<<<BB, 128, 0, stream>>>(avg, mxb, Wca1, Wca2, ca);
    k_sat<<<dim3(8, BB), 256, 0, stream>>>(conc, ca, s0, s1);
    k_gate<<<dim3(8, BB), 256, 0, stream>>>(conc, ca, s0, s1, Wsa, hidden, rh, ubuf);
    k_xw<64><<<dim3(125, BB), 64, 0, stream>>>(inputs, rh, W1b, zbuf);
    k_agg<<<dim3(32, 1, BB), 256, 0, stream>>>(mbuf, dinv, zbuf, b1b, cpre, 64);
    k_fin<<<(BB * NN * 64 + 255) / 256, 256, 0, stream>>>(ubuf, hidden, cpre, out);
}

// Round 2
// 486.341 us; speedup vs baseline: 4.4450x; 4.4450x over previous
//
#include <hip/hip_runtime.h>

#define NN 2000
#define BB 8
#define P  2048   // padded dim for all MFMA operands

typedef __attribute__((ext_vector_type(8))) short bf16x8;
typedef __attribute__((ext_vector_type(4))) float f32x4;

__device__ __forceinline__ float sigf(float x) { return 1.0f / (1.0f + expf(-x)); }

__device__ __forceinline__ short f2bf(float x) {
    union { float f; unsigned u; } v; v.f = x;
    unsigned r = v.u + 0x7fffu + ((v.u >> 16) & 1u);   // round-nearest-even
    return (short)(r >> 16);
}
__device__ __forceinline__ float bf2f(short h) {
    union { unsigned u; float f; } v; v.u = ((unsigned)(unsigned short)h) << 16; return v.f;
}

__device__ __forceinline__ void gl2lds16(const short* g, short* l) {
    __builtin_amdgcn_global_load_lds(
        (const __attribute__((address_space(1))) void*)g,
        (__attribute__((address_space(3))) void*)l, 16, 0, 0);
}

// ---------------------------------------------------------------------------
// cvtW: W2/W3/adj (fp32 [2000][2000]) -> bf16 [P][P] zero-padded
// ---------------------------------------------------------------------------
__global__ __launch_bounds__(256) void k_cvtW(
    const float* __restrict__ s0, const float* __restrict__ s1, const float* __restrict__ s2,
    short* __restrict__ d0, short* __restrict__ d1, short* __restrict__ d2)
{
    const int i = blockIdx.x, sel = blockIdx.y, t = threadIdx.x;
    const float* s = (sel == 0) ? s0 : (sel == 1) ? s1 : s2;
    short* d = ((sel == 0) ? d0 : (sel == 1) ? d1 : d2) + ((size_t)i) * P + t * 8;
    bf16x8 v;
#pragma unroll
    for (int e = 0; e < 8; ++e) v[e] = 0;
    if (i < NN && t < 250) {
        const float* p = s + (size_t)i * NN + t * 8;
        float4 x0 = *(const float4*)p;
        float4 x1 = *(const float4*)(p + 4);
        float a[8] = {x0.x,x0.y,x0.z,x0.w,x1.x,x1.y,x1.z,x1.w};
#pragma unroll
        for (int e = 0; e < 8; ++e) v[e] = f2bf(a[e]);
    }
    *(bf16x8*)d = v;
}

// ---------------------------------------------------------------------------
// cvtD1: d1bf[b][i][j] = bf16( relu(cos(|windd[i][j]-wn[b][i]| deg)) ), padded
// ---------------------------------------------------------------------------
__global__ __launch_bounds__(256) void k_cvtD1(
    const float* __restrict__ windd, const float* __restrict__ inputs, short* __restrict__ d1bf)
{
    const int i = blockIdx.x, b = blockIdx.y, t = threadIdx.x;
    short* d = d1bf + ((size_t)b * P + i) * P + t * 8;
    bf16x8 v;
#pragma unroll
    for (int e = 0; e < 8; ++e) v[e] = 0;
    if (i < NN && t < 250) {
        const float wn = inputs[(size_t)b * 3 * NN + 2 * NN + i] * 360.0f;
        const float* p = windd + (size_t)i * NN + t * 8;
        float4 x0 = *(const float4*)p;
        float4 x1 = *(const float4*)(p + 4);
        float a[8] = {x0.x,x0.y,x0.z,x0.w,x1.x,x1.y,x1.z,x1.w};
#pragma unroll
        for (int e = 0; e < 8; ++e) {
            float dd = fabsf(a[e] - wn);
            dd = (dd > 360.0f) ? 180.0f : dd;
            float c = __cosf(dd * 0.01745329251994329577f);
            v[e] = f2bf(fmaxf(c, 0.0f));
        }
    }
    *(bf16x8*)d = v;
}

// ---------------------------------------------------------------------------
// MFMA GEMM: C = A @ B^T, A/B bf16 row-major stride P, M=N=multiple of 128,
// K=P. 128x128 tile, 4 waves (2x2), 4x4 frags of 16x16x32, BK=32,
// global_load_lds(16B) staging (m97 structure).
// EPI 0: adjW3bf = bf16(acc + b3[col])                      [2000][2000]
// EPI 1: m_bf[b] = bf16(relu(acc + b2[col] + adjW3) + I)    [P][P] padded 0
// EPI 2: Cout[b][row*OUTD+col] = acc*dinv[b,row] + bias[col]  (fp32)
// ---------------------------------------------------------------------------
template<int EPI, int OUTD>
__global__ __launch_bounds__(256) void k_mfma(
    const short* __restrict__ Abase, const short* __restrict__ Bbase,
    const float* __restrict__ bias, const short* __restrict__ adjw,
    const float* __restrict__ dinv, void* __restrict__ Cout, size_t aBatch)
{
    __shared__ short shA[4096];
    __shared__ short shB[4096];
    const int t = threadIdx.x;
    const int w = t >> 6, lane = t & 63;
    const int wr = w >> 1, wc = w & 1;
    const int i0 = blockIdx.x * 128, j0 = blockIdx.y * 128;
    const int b = blockIdx.z;
    const short* A  = Abase + (size_t)b * aBatch;
    const short* Bm = Bbase + ((EPI == 2) ? (size_t)b * 128 * P : (size_t)0);

    f32x4 acc[4][4];
#pragma unroll
    for (int m = 0; m < 4; ++m)
#pragma unroll
        for (int n = 0; n < 4; ++n) acc[m][n] = (f32x4){0.f, 0.f, 0.f, 0.f};

    // staging geometry: 16B chunk index lidx -> row = lidx>>2, k-sub = (lidx&3)*8
    const int lidx0 = w * 128 + lane;
    const int lidx1 = lidx0 + 64;
    const short* aS0 = A  + (size_t)(i0 + (lidx0 >> 2)) * P + (lidx0 & 3) * 8;
    const short* aS1 = A  + (size_t)(i0 + (lidx1 >> 2)) * P + (lidx1 & 3) * 8;
    const short* bS0 = Bm + (size_t)(j0 + (lidx0 >> 2)) * P + (lidx0 & 3) * 8;
    const short* bS1 = Bm + (size_t)(j0 + (lidx1 >> 2)) * P + (lidx1 & 3) * 8;
    short* ldA0 = shA + (w * 128) * 8;         // wave-uniform LDS bases
    short* ldA1 = shA + (w * 128 + 64) * 8;
    short* ldB0 = shB + (w * 128) * 8;
    short* ldB1 = shB + (w * 128 + 64) * 8;

    const int lr = lane & 15, lq = lane >> 4;
    const int aoff = (wr * 64 + lr) * 32 + lq * 8;
    const int boff = (wc * 64 + lr) * 32 + lq * 8;

    for (int k0 = 0; k0 < P; k0 += 32) {
        gl2lds16(aS0 + k0, ldA0);
        gl2lds16(aS1 + k0, ldA1);
        gl2lds16(bS0 + k0, ldB0);
        gl2lds16(bS1 + k0, ldB1);
        __syncthreads();
        bf16x8 aF[4], bF[4];
#pragma unroll
        for (int m = 0; m < 4; ++m) aF[m] = *(const bf16x8*)(shA + aoff + m * 512);
#pragma unroll
        for (int n = 0; n < 4; ++n) bF[n] = *(const bf16x8*)(shB + boff + n * 512);
#pragma unroll
        for (int m = 0; m < 4; ++m)
#pragma unroll
            for (int n = 0; n < 4; ++n)
                acc[m][n] = __builtin_amdgcn_mfma_f32_16x16x32_bf16(aF[m], bF[n], acc[m][n], 0, 0, 0);
        __syncthreads();
    }

    const int rbase = i0 + wr * 64 + lq * 4;
    const int cbase = j0 + wc * 64 + lr;
#pragma unroll
    for (int m = 0; m < 4; ++m) {
#pragma unroll
        for (int n = 0; n < 4; ++n) {
            const int col = cbase + n * 16;
#pragma unroll
            for (int q = 0; q < 4; ++q) {
                const int row = rbase + m * 16 + q;
                float v = acc[m][n][q];
                if (EPI == 0) {
                    if (row < NN && col < NN)
                        ((short*)Cout)[(size_t)row * NN + col] = f2bf(v + bias[col]);
                } else if (EPI == 1) {
                    short o = 0;
                    if (row < NN && col < NN) {
                        float x = v + bias[col] + bf2f(adjw[(size_t)row * NN + col]);
                        x = fmaxf(x, 0.0f);
                        if (row == col) x += 1.0f;
                        o = f2bf(x);
                    }
                    ((short*)Cout)[((size_t)b * P + row) * P + col] = o;
                } else {
                    if (row < NN && col < OUTD)
                        ((float*)Cout)[((size_t)b * NN + row) * OUTD + col] =
                            v * dinv[b * NN + row] + bias[col];
                }
            }
        }
    }
}

// dinv[b,i] = rsqrt(sum_j m_bf[b][i][j])  (pads are zero)
__global__ __launch_bounds__(256) void k_rowsum_bf(const short* __restrict__ m_bf, float* __restrict__ dinv)
{
    const int i = blockIdx.x, b = blockIdx.y;
    const short* p = m_bf + ((size_t)b * P + i) * P + threadIdx.x * 8;
    bf16x8 v = *(const bf16x8*)p;
    float s = 0.0f;
#pragma unroll
    for (int e = 0; e < 8; ++e) s += bf2f(v[e]);
#pragma unroll
    for (int off = 32; off > 0; off >>= 1) s += __shfl_down(s, off);
    __shared__ float red[4];
    if ((threadIdx.x & 63) == 0) red[threadIdx.x >> 6] = s;
    __syncthreads();
    if (threadIdx.x == 0) dinv[b * NN + i] = rsqrtf(red[0] + red[1] + red[2] + red[3]);
}

// zT[b][o][j] = bf16( dinv[b,j] * sum_c x[b,j,c]*W[o,c] ), 128 rows, padded j
template<int OUT>
__global__ __launch_bounds__(128) void k_xwT(
    const float* __restrict__ inputs, const float* __restrict__ hsrc,
    const float* __restrict__ W, const float* __restrict__ dinv, short* __restrict__ zT)
{
    const int b = blockIdx.y;
    const int j0 = blockIdx.x * 16;
    const int t = threadIdx.x;
    __shared__ float wl[128 * 65];
    __shared__ float xs[16 * 66];
    __shared__ float dj[16];
    for (int idx = t; idx < OUT * 65; idx += 128) wl[idx] = W[idx];
    for (int idx = t; idx < 16 * 64; idx += 128) {
        int jj = idx >> 6, hh = idx & 63, j = j0 + jj;
        xs[jj * 66 + 1 + hh] = (j < NN) ? hsrc[((size_t)b * NN + j) * 64 + hh] : 0.0f;
    }
    if (t < 16) {
        int j = j0 + t;
        xs[t * 66] = (j < NN) ? inputs[(size_t)b * 3 * NN + j] : 0.0f;
        dj[t] = (j < NN) ? dinv[b * NN + j] : 0.0f;
    }
    __syncthreads();
    for (int jj = 0; jj < 16; ++jj) {
        float a = 0.0f;
        if (t < OUT) {
            const float* xr = &xs[jj * 66];
            const float* wr = &wl[t * 65];
#pragma unroll
            for (int c = 0; c < 65; ++c) a = fmaf(xr[c], wr[c], a);
        }
        int j = j0 + jj;
        zT[((size_t)b * 128 + t) * P + j] = (t < OUT && j < NN) ? f2bf(a * dj[jj]) : (short)0;
    }
}

// per (b,c): mean & max over conc[b, c*2000 : +2000]
__global__ __launch_bounds__(256) void k_chred(const float* __restrict__ conc,
                                               float* __restrict__ avg, float* __restrict__ mx)
{
    const int bc = blockIdx.x;
    const float* p = conc + (size_t)bc * NN;
    float s = 0.0f, mv = -3.402823466e+38f;
    for (int n = threadIdx.x; n < NN; n += 256) { float v = p[n]; s += v; mv = fmaxf(mv, v); }
#pragma unroll
    for (int off = 32; off > 0; off >>= 1) {
        s += __shfl_down(s, off);
        mv = fmaxf(mv, __shfl_down(mv, off));
    }
    __shared__ float rs[4], rm[4];
    if ((threadIdx.x & 63) == 0) { rs[threadIdx.x >> 6] = s; rm[threadIdx.x >> 6] = mv; }
    __syncthreads();
    if (threadIdx.x == 0) {
        avg[bc] = (rs[0] + rs[1] + rs[2] + rs[3]) * (1.0f / NN);
        mx[bc]  = fmaxf(fmaxf(rm[0], rm[1]), fmaxf(rm[2], rm[3]));
    }
}

__global__ __launch_bounds__(128) void k_ca(
    const float* __restrict__ avg, const float* __restrict__ mx,
    const float* __restrict__ Wca1, const float* __restrict__ Wca2, float* __restrict__ ca)
{
    const int b = blockIdx.x, t = threadIdx.x;
    __shared__ float av[128], mv[128], h[16];
    av[t] = avg[b * 128 + t];
    mv[t] = mx[b * 128 + t];
    __syncthreads();
    if (t < 16) {
        int o8 = t & 7;
        const float* src = (t < 8) ? av : mv;
        float s = 0.0f;
        for (int c = 0; c < 128; ++c) s = fmaf(Wca1[o8 * 128 + c], src[c], s);
        h[t] = fmaxf(s, 0.0f);
    }
    __syncthreads();
    float s = 0.0f;
#pragma unroll
    for (int k = 0; k < 8; ++k) s = fmaf(Wca2[t * 8 + k], h[k] + h[8 + k], s);
    ca[b * 128 + t] = sigf(s);
}

__global__ __launch_bounds__(256) void k_sat(
    const float* __restrict__ conc, const float* __restrict__ ca,
    float* __restrict__ s0, float* __restrict__ s1)
{
    const int b = blockIdx.y;
    const int n = blockIdx.x * 256 + threadIdx.x;
    __shared__ float cas[128];
    if (threadIdx.x < 128) cas[threadIdx.x] = ca[b * 128 + threadIdx.x];
    __syncthreads();
    if (n >= NN) return;
    float sm = 0.0f, sx = -3.402823466e+38f;
    for (int c = 0; c < 128; ++c) {
        float v = cas[c] * conc[(size_t)b * NN * 128 + (size_t)c * NN + n];
        sm += v; sx = fmaxf(sx, v);
    }
    s0[b * NN + n] = sm * (1.0f / 128.0f);
    s1[b * NN + n] = sx;
}

__global__ __launch_bounds__(256) void k_gate(
    const float* __restrict__ conc, const float* __restrict__ ca,
    const float* __restrict__ s0, const float* __restrict__ s1,
    const float* __restrict__ Wsa, const float* __restrict__ hidden,
    float* __restrict__ rh, float* __restrict__ u)
{
    const int b = blockIdx.y;
    const int n = blockIdx.x * 256 + threadIdx.x;
    __shared__ float cas[128];
    __shared__ float wsa[14];
    if (threadIdx.x < 128) cas[threadIdx.x] = ca[b * 128 + threadIdx.x];
    if (threadIdx.x < 14) wsa[threadIdx.x] = Wsa[threadIdx.x];
    __syncthreads();
    if (n >= NN) return;
    float sa = 0.0f;
#pragma unroll
    for (int k = 0; k < 7; ++k) {
        int nn = n + k - 3;
        if (nn >= 0 && nn < NN)
            sa += wsa[k] * s0[b * NN + nn] + wsa[7 + k] * s1[b * NN + nn];
    }
    float gs = sigf(sa);
    for (int c = 0; c < 128; ++c) {
        float v = gs * cas[c] * conc[(size_t)b * NN * 128 + (size_t)c * NN + n];
        float g = sigf(v);
        if (c < 64)
            rh[(size_t)b * NN * 64 + (size_t)c * NN + n] =
                g * hidden[(size_t)b * NN * 64 + (size_t)c * NN + n];
        else
            u[(size_t)b * NN * 64 + (size_t)(c - 64) * NN + n] = g;
    }
}

__global__ __launch_bounds__(256) void k_fin(
    const float* __restrict__ u, const float* __restrict__ hidden,
    const float* __restrict__ cpre, float* __restrict__ out)
{
    const size_t idx = (size_t)blockIdx.x * 256 + threadIdx.x;
    if (idx >= (size_t)BB * NN * 64) return;
    float uu = u[idx];
    out[idx] = uu * hidden[idx] + (1.0f - uu) * tanhf(cpre[idx]);
}

extern "C" void kernel_launch(void* const* d_in, const int* in_sizes, int n_in,
                              void* d_out, int out_size, void* d_ws, size_t ws_size,
                              hipStream_t stream)
{
    (void)in_sizes; (void)n_in; (void)out_size; (void)ws_size;
    const float* inputs = (const float*)d_in[0];
    const float* hidden = (const float*)d_in[1];
    const float* adj    = (const float*)d_in[2];
    const float* windd  = (const float*)d_in[3];
    const float* W2     = (const float*)d_in[4];
    const float* b2     = (const float*)d_in[5];
    const float* W3     = (const float*)d_in[6];
    const float* b3     = (const float*)d_in[7];
    const float* W1a    = (const float*)d_in[8];
    const float* b1a    = (const float*)d_in[9];
    const float* W1b    = (const float*)d_in[10];
    const float* b1b    = (const float*)d_in[11];
    const float* Wca1   = (const float*)d_in[12];
    const float* Wca2   = (const float*)d_in[13];
    const float* Wsa    = (const float*)d_in[14];
    float* out = (float*)d_out;

    // ---- workspace layout (byte offsets; unions by lifetime) ----
    char* W = (char*)d_ws;
    short* adjW3bf = (short*)(W + 0);            // [2000][2000] bf16, 8,000,000 B
    short* W2bf    = (short*)(W + 8000000);      // [P][P] bf16, 8,388,608 B
    // unionC: {W3bf, adjbf} (early) then m_bf [BB][P][P] (67,108,864 B)
    short* W3bf    = (short*)(W + 16388608);
    short* adjbf   = (short*)(W + 24777216);
    short* m_bf    = (short*)(W + 16388608);
    // unionD: d1bf (early, 67,108,864 B) then post-GEMM1 buffers
    char* D = W + 83497472;
    short* d1bf = (short*)D;
    float* dinv = (float*)(D + 0);
    float* avgb = (float*)(D + 64000);
    float* mxb  = (float*)(D + 68096);
    float* cab  = (float*)(D + 72192);
    float* s0b  = (float*)(D + 76288);
    float* s1b  = (float*)(D + 140288);
    short* zT   = (short*)(D + 204800);
    float* conc = (float*)(D + 4399104);
    float* rh   = (float*)(D + 12591104);
    float* ubuf = (float*)(D + 16687104);
    float* cpre = (float*)(D + 20783104);

    const size_t PP = (size_t)P * P;

    k_cvtW<<<dim3(P, 3), 256, 0, stream>>>(W2, W3, adj, W2bf, W3bf, adjbf);
    k_cvtD1<<<dim3(P, BB), 256, 0, stream>>>(windd, inputs, d1bf);
    k_mfma<0, 0><<<dim3(16, 16, 1), 256, 0, stream>>>(adjbf, W3bf, b3, nullptr, nullptr, adjW3bf, 0);
    k_mfma<1, 0><<<dim3(16, 16, BB), 256, 0, stream>>>(d1bf, W2bf, b2, adjW3bf, nullptr, m_bf, PP);
    k_rowsum_bf<<<dim3(NN, BB), 256, 0, stream>>>(m_bf, dinv);
    k_xwT<128><<<dim3(128, BB), 128, 0, stream>>>(inputs, hidden, W1a, dinv, zT);
    k_mfma<2, 128><<<dim3(16, 1, BB), 256, 0, stream>>>(m_bf, zT, b1a, nullptr, dinv, conc, PP);
    k_chred<<<BB * 128, 256, 0, stream>>>(conc, avgb, mxb);
    k_ca<<<BB, 128, 0, stream>>>(avgb, mxb, Wca1, Wca2, cab);
    k_sat<<<dim3(8, BB), 256, 0, stream>>>(conc, cab, s0b, s1b);
    k_gate<<<dim3(8, BB), 256, 0, stream>>>(conc, cab, s0b, s1b, Wsa, hidden, rh, ubuf);
    k_xwT<64><<<dim3(128, BB), 128, 0, stream>>>(inputs, rh, W1b, dinv, zT);
    k_mfma<2, 64><<<dim3(16, 1, BB), 256, 0, stream>>>(m_bf, zT, b1b, nullptr, dinv, cpre, PP);
    k_fin<<<(BB * NN * 64 + 255) / 256, 256, 0, stream>>>(ubuf, hidden, cpre, out);
}